// Round 10
// baseline (183.193 us; speedup 1.0000x reference)
//
#include <hip/hip_runtime.h>
#include <hip/hip_bf16.h>
#include <math.h>

typedef __hip_bfloat16 bf16;
typedef _Float16 f16;
typedef __attribute__((ext_vector_type(8))) short bf16x8;
typedef __attribute__((ext_vector_type(8))) _Float16 f16x8;
typedef __attribute__((ext_vector_type(4))) float f32x4;
typedef __attribute__((ext_vector_type(4))) unsigned u32x4;

#define MFMA_BF(a,b,c) __builtin_amdgcn_mfma_f32_16x16x32_bf16((a),(b),(c),0,0,0)
#define MFMA_F16(a,b,c) __builtin_amdgcn_mfma_f32_16x16x32_f16((a),(b),(c),0,0,0)

__device__ __forceinline__ void load_lds16(const void* g, void* l) {
  __builtin_amdgcn_global_load_lds(
      (__attribute__((address_space(1))) void*)(g),
      (__attribute__((address_space(3))) void*)(l), 16, 0, 0);
}

// RTNE f32->bf16 pair pack (same bit-path the old cvt_all kernel used)
__device__ __forceinline__ unsigned pk_bf16(float a, float b) {
  unsigned ua = __builtin_bit_cast(unsigned, a);
  unsigned ub = __builtin_bit_cast(unsigned, b);
  ua += 0x7fffu + ((ua >> 16) & 1u);
  ub += 0x7fffu + ((ub >> 16) & 1u);
  return (ua >> 16) | (ub & 0xffff0000u);
}

// ---------------- merged QKV GEMM, fp32 inputs: C[M,3072] = x * Wqkv^T --------------
// ROUND 10: cvt_all kernel DELETED (launch-gap ~6-13us/kernel + 8us work + 28MB HBM
// round-trip). gemm_qkv reads fp32 x / W_qkv directly: reg-staged float4 loads +
// RTNE pack + ds_write_b128 to the SAME linear LDS layout global_load_lds produced
// (fragment reads untouched). 2-buffer LDS (16KB), 1 barrier/chunk; loads for c+2
// issued at end of iteration c (full chunk of latency cover). wout fp32->bf16 is a
// grid-stride tail here (~1us). Epilogues/compute identical to r6-measured state.
__global__ __launch_bounds__(256, 3)
void gemm_qkv(const float* __restrict__ A, const float* __restrict__ B,
              const float* __restrict__ Wo,
              bf16* __restrict__ outq, bf16* __restrict__ outk,
              f16* __restrict__ outv, bf16* __restrict__ woutb) {
  __shared__ __align__(16) bf16 As[2][128 * 32];   // 8 KB
  __shared__ __align__(16) bf16 Bs[2][128 * 32];   // 8 KB
  const int K = 1024;
  const int tid = threadIdx.x;
  const int w = tid >> 6;
  const int lane = tid & 63;
  const int quad = lane >> 4;
  const int col = lane & 15;
  const int waveM = w >> 1;
  const int waveN = w & 1;
  const int bm = blockIdx.y * 128;
  const int bn = blockIdx.x * 128;

  f32x4 acc[4][4] = {};
  const int srow = lane >> 2;                                  // 0..15
  const int skoff = (((lane & 3) ^ ((srow >> 1) & 3))) * 8;    // swizzled src block (elems)
  const int swq = (quad ^ ((col >> 1) & 3)) * 8;               // swizzled frag offset

  // in-flight chunk data: 8 float4 = 32 VGPRs
  float4 rA[2][2], rB[2][2];

  auto issue = [&](int k0) {
#pragma unroll
    for (int p = 0; p < 2; ++p) {
      int r = p * 64 + w * 16 + srow;
      const float4* pa = reinterpret_cast<const float4*>(A + (size_t)(bm + r) * K + k0 + skoff);
      rA[p][0] = pa[0];
      rA[p][1] = pa[1];
      const float4* pb = reinterpret_cast<const float4*>(B + (size_t)(bn + r) * K + k0 + skoff);
      rB[p][0] = pb[0];
      rB[p][1] = pb[1];
    }
  };
  // pack + ds_write to the exact bytes global_load_lds used to write
  auto writeLds = [&](int sb) {
#pragma unroll
    for (int p = 0; p < 2; ++p) {
      uint4 ua, ub;
      ua.x = pk_bf16(rA[p][0].x, rA[p][0].y);
      ua.y = pk_bf16(rA[p][0].z, rA[p][0].w);
      ua.z = pk_bf16(rA[p][1].x, rA[p][1].y);
      ua.w = pk_bf16(rA[p][1].z, rA[p][1].w);
      *reinterpret_cast<uint4*>((char*)As + sb * 8192 + p * 4096 + w * 1024 + lane * 16) = ua;
      ub.x = pk_bf16(rB[p][0].x, rB[p][0].y);
      ub.y = pk_bf16(rB[p][0].z, rB[p][0].w);
      ub.z = pk_bf16(rB[p][1].x, rB[p][1].y);
      ub.w = pk_bf16(rB[p][1].z, rB[p][1].w);
      *reinterpret_cast<uint4*>((char*)Bs + sb * 8192 + p * 4096 + w * 1024 + lane * 16) = ub;
    }
  };

  // prologue: chunk0 -> LDS buf0 (compiler auto-waits vmcnt for rA/rB use);
  // chunk1 loads left in flight in regs.
  issue(0);
  writeLds(0);
  issue(32);

  int cb = 0;
  for (int k0 = 0; k0 < K; k0 += 32) {
    // my prior ds_writes must be visible to all waves past this barrier
    __asm__ volatile("s_waitcnt lgkmcnt(0)" ::: "memory");
    __asm__ volatile("s_barrier" ::: "memory");

    const bf16* at = &As[cb][0];
    const bf16* bt = &Bs[cb][0];
    bf16x8 af[4], bfr[4];
#pragma unroll
    for (int i = 0; i < 4; ++i)
      af[i] = *reinterpret_cast<const bf16x8*>(at + (waveM * 64 + i * 16 + col) * 32 + swq);
#pragma unroll
    for (int j = 0; j < 4; ++j)
      bfr[j] = *reinterpret_cast<const bf16x8*>(bt + (waveN * 64 + j * 16 + col) * 32 + swq);
#pragma unroll
    for (int i = 0; i < 4; ++i)
#pragma unroll
      for (int j = 0; j < 4; ++j)
        acc[i][j] = MFMA_BF(af[i], bfr[j], acc[i][j]);

    if (k0 + 32 < K) {
      // regs hold chunk k0+32 (issued last iteration); write into the buffer
      // that chunk k0-32 used -- all waves finished reading it before the
      // barrier above, and my writes are after it -> safe.
      writeLds(cb ^ 1);
      if (k0 + 64 < K) issue(k0 + 64);
    }
    cb ^= 1;
  }

  if (bn < 2048) {
    // ---- fused RoPE + store [bh][t][d]; q scaled by 0.125*log2e ----
    const float NEGK = -0.4152410118f;  // -log2(10000)/32
    const float C1 = 0.1803368799f;     // 0.125 * log2(e)
    const float sgn = (col & 1) ? 1.0f : -1.0f;
#pragma unroll
    for (int j = 0; j < 4; ++j) {
      const int n0 = bn + waveN * 64 + j * 16;
      const int sel = n0 >> 10;                 // 0=q, 1=k
      const int hh = (n0 & 1023) >> 6;
      const int dd = (n0 & 63) + col;
      bf16* outp = sel ? outk : outq;
      const float post = sel ? 1.0f : C1;
      const float invf = __builtin_amdgcn_exp2f((float)((n0 & 31) + col) * NEGK);
#pragma unroll
      for (int i = 0; i < 4; ++i) {
#pragma unroll
        for (int r = 0; r < 4; ++r) {
          int m = bm + waveM * 64 + i * 16 + quad * 4 + r;
          int b = m >> 11, t = m & 2047;
          float v = acc[i][j][r];
          float partner = __shfl_xor(v, 1);
          float ang = (float)t * invf;
          float res = (v * __cosf(ang) + sgn * partner * __sinf(ang)) * post;
          outp[((size_t)(b * 16 + hh) * 2048 + t) * 64 + dd] = __float2bfloat16(res);
        }
      }
    }
  } else {
    // ---- V region: acc rows are t-consecutive -> pack 4 t's into b64 stores ----
    const int b = bm >> 11;
    const int tt0 = (bm & 2047) + waveM * 64;
#pragma unroll
    for (int j = 0; j < 4; ++j) {
      const int n0 = bn + waveN * 64 + j * 16;
      const int hh = (n0 & 1023) >> 6;
      const int dd = (n0 & 63) + col;
      f16* dst = outv + (size_t)(b * 16 + hh) * 131072 + (size_t)dd * 2048;
#pragma unroll
      for (int i = 0; i < 4; ++i) {
        uint2 pk;
        pk.x = __builtin_bit_cast(unsigned, __builtin_amdgcn_cvt_pkrtz(acc[i][j][0], acc[i][j][1]));
        pk.y = __builtin_bit_cast(unsigned, __builtin_amdgcn_cvt_pkrtz(acc[i][j][2], acc[i][j][3]));
        *reinterpret_cast<uint2*>(dst + tt0 + i * 16 + quad * 4) = pk;
      }
    }
  }

  // ---- wout fp32->bf16 tail (replaces the rest of cvt_all): 262144 float4s ----
  {
    int gid = (blockIdx.y * gridDim.x + blockIdx.x) * 256 + tid;   // 0..196607
    for (int i = gid; i < 262144; i += 196608) {
      float4 v = reinterpret_cast<const float4*>(Wo)[i];
      uint2 u;
      u.x = pk_bf16(v.x, v.y);
      u.y = pk_bf16(v.z, v.w);
      reinterpret_cast<uint2*>(woutb)[i] = u;
    }
  }
}

// ---------------- output GEMM: out[4096,1024] = y[4096,1024] * Wout^T ----------------
// FROZEN (r6-measured): 128x128 tile, 512 threads / 8 waves, grid (8,32) = 1 block/CU.
__global__ __launch_bounds__(512, 2)
void gemm_out(const bf16* __restrict__ A, const bf16* __restrict__ B,
              float* __restrict__ outf) {
  __shared__ __align__(16) bf16 As[3][128 * 32];
  __shared__ __align__(16) bf16 Bs[3][128 * 32];
  const int K = 1024;
  const int tid = threadIdx.x;
  const int w = tid >> 6;          // 0..7
  const int lane = tid & 63;
  const int quad = lane >> 4;
  const int col = lane & 15;
  const int waveM = w >> 2;
  const int waveN = w & 3;
  const int bm = blockIdx.y * 128;
  const int bn = blockIdx.x * 128;

  f32x4 acc[4][2] = {};
  const int srow = lane >> 2;
  const int skoff = (((lane & 3) ^ ((srow >> 1) & 3))) * 8;
  const int swq = (quad ^ ((col >> 1) & 3)) * 8;

  auto stage = [&](int k0, int sb) {
    int r = w * 16 + srow;
    load_lds16(A + (size_t)(bm + r) * K + k0 + skoff,
               (char*)As + sb * 8192 + w * 1024);
    load_lds16(B + (size_t)(bn + r) * K + k0 + skoff,
               (char*)Bs + sb * 8192 + w * 1024);
  };

  stage(0, 0);
  stage(32, 1);

  int cb = 0;
  for (int k0 = 0; k0 < K; k0 += 32) {
    if (k0 + 32 < K) __asm__ volatile("s_waitcnt vmcnt(2)" ::: "memory");
    else             __asm__ volatile("s_waitcnt vmcnt(0)" ::: "memory");
    __asm__ volatile("s_barrier" ::: "memory");
    if (k0 + 64 < K) {
      int nb = cb + 2; if (nb >= 3) nb -= 3;
      stage(k0 + 64, nb);
    }
    const bf16* at = &As[cb][0];
    const bf16* bt = &Bs[cb][0];
    bf16x8 af[4], bfr[2];
#pragma unroll
    for (int i = 0; i < 4; ++i)
      af[i] = *reinterpret_cast<const bf16x8*>(at + (waveM * 64 + i * 16 + col) * 32 + swq);
#pragma unroll
    for (int j = 0; j < 2; ++j)
      bfr[j] = *reinterpret_cast<const bf16x8*>(bt + (waveN * 32 + j * 16 + col) * 32 + swq);
#pragma unroll
    for (int i = 0; i < 4; ++i)
#pragma unroll
      for (int j = 0; j < 2; ++j)
        acc[i][j] = MFMA_BF(af[i], bfr[j], acc[i][j]);
    cb = (cb == 2) ? 0 : cb + 1;
  }

#pragma unroll
  for (int i = 0; i < 4; ++i)
#pragma unroll
    for (int j = 0; j < 2; ++j) {
      const int n0 = bn + waveN * 32 + j * 16;
#pragma unroll
      for (int r = 0; r < 4; ++r) {
        int m = bm + waveM * 64 + i * 16 + quad * 4 + r;
        outf[(size_t)m * 1024 + n0 + col] = acc[i][j][r];
      }
    }
}

// ---------------- flash attention: KVBLK=128, halved sync density ----------------
// FROZEN (r9-measured, 43.8us): 128-key chunks as two 64-key sub-tiles, 1 sync per
// 128 keys, 80KB LDS = 2 blocks/CU, PV lags S by one chunk, XCD = bh%8 locality.
__global__ __launch_bounds__(256, 2)
void attn_kernel(const bf16* __restrict__ qh, const bf16* __restrict__ kh,
                 const f16* __restrict__ vt, bf16* __restrict__ y) {
  __shared__ __align__(16) bf16 Ks[2][2 * 64 * 64];   // 32 KB
  __shared__ __align__(16) f16 Vs[3][2 * 64 * 64];    // 48 KB

  const int bh = blockIdx.x;          // XCD = bh % 8
  const int qt = blockIdx.y;
  const int w = threadIdx.x >> 6;
  const int lane = threadIdx.x & 63;
  const int quad = lane >> 4;
  const int col = lane & 15;

  const int qrow0 = qt * 128 + w * 32 + col;
  bf16x8 qf[2][2];
#pragma unroll
  for (int f = 0; f < 2; ++f)
#pragma unroll
    for (int c = 0; c < 2; ++c)
      qf[f][c] = *reinterpret_cast<const bf16x8*>(
          qh + ((size_t)bh * 2048 + qrow0 + f * 16) * 64 + c * 32 + quad * 8);

  const int s8 = lane >> 3;
  const int blk = (lane & 7) ^ s8;
  const bf16* kg = kh + (size_t)bh * 2048 * 64;
  const f16* vg = vt + (size_t)bh * 64 * 2048;
  // kappa permutation for LDS row p = w*16 + 8L + s8 (per 64-key sub-tile)
  const int ks0 = 32 * (w >> 1) + 8 * ((4 * w + (s8 >> 2)) & 3) + 4 * (w & 1) + (s8 & 3);
  const int ks1 = 32 * (w >> 1) + 8 * ((4 * w + 2 + (s8 >> 2)) & 3) + 4 * (w & 1) + (s8 & 3);
  const int vrow0 = w * 16 + s8;   // V rows = d, identity keys

  const int csw = col & 7;
  const int sw0 = (quad ^ csw) * 8;
  const int sw1 = ((quad + 4) ^ csw) * 8;
  const int rdbase = col * 64;

  f32x4 O[2][4] = {};
  float l[2] = {};
  f16x8 pf[2][4];      // P fragments of the PREVIOUS 128-key chunk

  auto stageK2 = [&](int kn, int kb) {
    char* kbp = (char*)Ks + kb * 16384 + w * 2048;
    load_lds16(kg + (size_t)(kn + ks0) * 64 + blk * 8, kbp);
    load_lds16(kg + (size_t)(kn + ks1) * 64 + blk * 8, kbp + 1024);
    load_lds16(kg + (size_t)(kn + 64 + ks0) * 64 + blk * 8, kbp + 8192);
    load_lds16(kg + (size_t)(kn + 64 + ks1) * 64 + blk * 8, kbp + 8192 + 1024);
  };
  auto stageV2 = [&](int kn, int vb) {
    char* vbp = (char*)Vs + vb * 16384 + w * 2048;
    load_lds16(vg + (size_t)vrow0 * 2048 + kn + blk * 8, vbp);
    load_lds16(vg + (size_t)(vrow0 + 8) * 2048 + kn + blk * 8, vbp + 1024);
    load_lds16(vg + (size_t)vrow0 * 2048 + kn + 64 + blk * 8, vbp + 8192);
    load_lds16(vg + (size_t)(vrow0 + 8) * 2048 + kn + 64 + blk * 8, vbp + 8192 + 1024);
  };

  auto softmax = [&](f32x4 (&s)[2][2][4]) {
#pragma unroll
    for (int f = 0; f < 2; ++f) {
      unsigned pk[16];
      float lf = 0.0f;
#pragma unroll
      for (int u = 0; u < 2; ++u)
#pragma unroll
        for (int t = 0; t < 4; ++t) {
          float p0 = __builtin_amdgcn_exp2f(s[f][u][t][0]);
          float p1 = __builtin_amdgcn_exp2f(s[f][u][t][1]);
          float p2 = __builtin_amdgcn_exp2f(s[f][u][t][2]);
          float p3 = __builtin_amdgcn_exp2f(s[f][u][t][3]);
          lf += (p0 + p1) + (p2 + p3);
          pk[u * 8 + t * 2]     = __builtin_bit_cast(unsigned, __builtin_amdgcn_cvt_pkrtz(p0, p1));
          pk[u * 8 + t * 2 + 1] = __builtin_bit_cast(unsigned, __builtin_amdgcn_cvt_pkrtz(p2, p3));
        }
      l[f] += lf;
      pf[f][0] = __builtin_bit_cast(f16x8, (u32x4){pk[0], pk[1], pk[2], pk[3]});
      pf[f][1] = __builtin_bit_cast(f16x8, (u32x4){pk[4], pk[5], pk[6], pk[7]});
      pf[f][2] = __builtin_bit_cast(f16x8, (u32x4){pk[8], pk[9], pk[10], pk[11]});
      pf[f][3] = __builtin_bit_cast(f16x8, (u32x4){pk[12], pk[13], pk[14], pk[15]});
    }
  };

  // ---- prologue: chunk 0 staged; peeled iteration 0 (S + softmax only) ----
  stageK2(0, 0);
  stageV2(0, 0);

  __asm__ volatile("s_waitcnt vmcnt(4)" ::: "memory");   // K(0) done, V(0) x4 in flight
  __asm__ volatile("s_barrier" ::: "memory");
  stageK2(128, 1);
  stageV2(128, 1);
  {
    f32x4 s[2][2][4];
    __builtin_amdgcn_s_setprio(1);
#pragma unroll
    for (int u = 0; u < 2; ++u) {
      const bf16* kt = &Ks[0][u * 4096];
#pragma unroll
      for (int t = 0; t < 4; ++t) {
        bf16x8 kf0 = *reinterpret_cast<const bf16x8*>(kt + t * 1024 + rdbase + sw0);
        bf16x8 kf1 = *reinterpret_cast<const bf16x8*>(kt + t * 1024 + rdbase + sw1);
#pragma unroll
        for (int f = 0; f < 2; ++f) {
          f32x4 a = {};
          a = MFMA_BF(kf0, qf[f][0], a);
          a = MFMA_BF(kf1, qf[f][1], a);
          s[f][u][t] = a;
        }
      }
    }
    __builtin_amdgcn_s_setprio(0);
    softmax(s);
  }

  // ---- main loop c = 1..15: S(c) + PV(c-1) fused MFMA cluster, 1 sync/128 keys ----
  int vprev = 0;
  int vnext = 2;
#pragma unroll 1
  for (int c = 1; c < 16; ++c) {
    const int kc = c * 128;
    __asm__ volatile("s_waitcnt vmcnt(4)" ::: "memory");
    __asm__ volatile("s_barrier" ::: "memory");
    if (c + 1 < 16) {
      stageK2(kc + 128, (c + 1) & 1);
      stageV2(kc + 128, vnext);
    }

    f32x4 s[2][2][4];
    __builtin_amdgcn_s_setprio(1);
#pragma unroll
    for (int u = 0; u < 2; ++u) {
      const bf16* kt = &Ks[c & 1][u * 4096];
      const f16* vtile = &Vs[vprev][u * 4096];
#pragma unroll
      for (int t = 0; t < 4; ++t) {
        bf16x8 kf0 = *reinterpret_cast<const bf16x8*>(kt + t * 1024 + rdbase + sw0);
        bf16x8 kf1 = *reinterpret_cast<const bf16x8*>(kt + t * 1024 + rdbase + sw1);
        f16x8 vf0 = *reinterpret_cast<const f16x8*>(vtile + t * 1024 + rdbase + sw0);
        f16x8 vf1 = *reinterpret_cast<const f16x8*>(vtile + t * 1024 + rdbase + sw1);
#pragma unroll
        for (int f = 0; f < 2; ++f) {
          f32x4 a = {};
          a = MFMA_BF(kf0, qf[f][0], a);
          a = MFMA_BF(kf1, qf[f][1], a);
          s[f][u][t] = a;
          O[f][t] = MFMA_F16(vf0, pf[f][u * 2], O[f][t]);
          O[f][t] = MFMA_F16(vf1, pf[f][u * 2 + 1], O[f][t]);
        }
      }
    }
    __builtin_amdgcn_s_setprio(0);
    softmax(s);

    vprev = (vprev == 2) ? 0 : vprev + 1;
    vnext = (vnext == 2) ? 0 : vnext + 1;
  }

  // ---- epilogue: final PV for chunk 15 ----
  __asm__ volatile("s_waitcnt vmcnt(0)" ::: "memory");
  __asm__ volatile("s_barrier" ::: "memory");
  {
    __builtin_amdgcn_s_setprio(1);
#pragma unroll
    for (int u = 0; u < 2; ++u) {
      const f16* vtile = &Vs[vprev][u * 4096];
#pragma unroll
      for (int t = 0; t < 4; ++t) {
        f16x8 vf0 = *reinterpret_cast<const f16x8*>(vtile + t * 1024 + rdbase + sw0);
        f16x8 vf1 = *reinterpret_cast<const f16x8*>(vtile + t * 1024 + rdbase + sw1);
#pragma unroll
        for (int f = 0; f < 2; ++f) {
          O[f][t] = MFMA_F16(vf0, pf[f][u * 2], O[f][t]);
          O[f][t] = MFMA_F16(vf1, pf[f][u * 2 + 1], O[f][t]);
        }
      }
    }
    __builtin_amdgcn_s_setprio(0);
  }

  // ---- reduce l over quads, normalize, direct y write ----
  const int b = bh >> 4, h = bh & 15;
#pragma unroll
  for (int f = 0; f < 2; ++f) {
    float lv = l[f];
    lv += __shfl_xor(lv, 16, 64);
    lv += __shfl_xor(lv, 32, 64);
    float inv = 1.0f / lv;
    int tq = qt * 128 + w * 32 + f * 16 + col;
    size_t base = ((size_t)b * 2048 + tq) * 1024 + h * 64;
#pragma unroll
    for (int j = 0; j < 4; ++j) {
      uint2 pk2;
      pk2.x = pk_bf16(O[f][j][0] * inv, O[f][j][1] * inv);
      pk2.y = pk_bf16(O[f][j][2] * inv, O[f][j][3] * inv);
      *reinterpret_cast<uint2*>((unsigned short*)y + base + j * 16 + quad * 4) = pk2;
    }
  }
}

extern "C" void kernel_launch(void* const* d_in, const int* in_sizes, int n_in,
                              void* d_out, int out_size, void* d_ws, size_t ws_size,
                              hipStream_t stream) {
  const float* x    = (const float*)d_in[0];
  const float* wqkv = (const float*)d_in[1];
  const float* wout = (const float*)d_in[2];
  float* out = (float*)d_out;
  char* ws = (char*)d_ws;

  bf16* woutb = (bf16*)(ws);                        // 2 MB
  bf16* qh    = (bf16*)(ws + (size_t)(2 << 20));    // 8 MB
  bf16* kh    = (bf16*)(ws + (size_t)(10 << 20));   // 8 MB
  f16*  vt    = (f16*) (ws + (size_t)(18 << 20));   // 8 MB
  bf16* y     = (bf16*)(ws + (size_t)(26 << 20));   // 8 MB  (total 34 MB)

  gemm_qkv<<<dim3(24, 32), 256, 0, stream>>>(x, wqkv, wout, qh, kh, vt, woutb);
  attn_kernel<<<dim3(32, 16), 256, 0, stream>>>(qh, kh, vt, y);
  gemm_out<<<dim3(8, 32), 512, 0, stream>>>(y, woutb, out);
}

// Round 11
// 176.000 us; speedup vs baseline: 1.0409x; 1.0409x over previous
//
#include <hip/hip_runtime.h>
#include <hip/hip_bf16.h>
#include <math.h>

typedef __hip_bfloat16 bf16;
typedef _Float16 f16;
typedef __attribute__((ext_vector_type(8))) short bf16x8;
typedef __attribute__((ext_vector_type(8))) _Float16 f16x8;
typedef __attribute__((ext_vector_type(4))) float f32x4;
typedef __attribute__((ext_vector_type(4))) unsigned u32x4;

#define MFMA_BF(a,b,c) __builtin_amdgcn_mfma_f32_16x16x32_bf16((a),(b),(c),0,0,0)
#define MFMA_F16(a,b,c) __builtin_amdgcn_mfma_f32_16x16x32_f16((a),(b),(c),0,0,0)

__device__ __forceinline__ void load_lds16(const void* g, void* l) {
  __builtin_amdgcn_global_load_lds(
      (__attribute__((address_space(1))) void*)(g),
      (__attribute__((address_space(3))) void*)(l), 16, 0, 0);
}

// RTNE f32->bf16 pair pack (software path -- used only in low-count epilogues)
__device__ __forceinline__ unsigned pk_bf16(float a, float b) {
  unsigned ua = __builtin_bit_cast(unsigned, a);
  unsigned ub = __builtin_bit_cast(unsigned, b);
  ua += 0x7fffu + ((ua >> 16) & 1u);
  ub += 0x7fffu + ((ub >> 16) & 1u);
  return (ua >> 16) | (ub & 0xffff0000u);
}

// HW RTNE f32-pair -> packed bf16: 1 VALU op (no builtin on gfx950; inline asm).
// r10 post-mortem: software pk_bf16 in the staging path was ~50 VALU ops/thread/chunk
// = ~1100 cyc/CU-iter -- the entire fused-qkv slowdown. This is the fix.
__device__ __forceinline__ unsigned cvtpk_bf16(float a, float b) {
  unsigned r;
  __asm__("v_cvt_pk_bf16_f32 %0, %1, %2" : "=v"(r) : "v"(a), "v"(b));
  return r;
}

// ---------------- merged QKV GEMM, fp32 inputs: C[M,3072] = x * Wqkv^T --------------
// cvt_all kernel deleted (r10); staging converts fp32->bf16 in-register.
// ROUND 11: staging pack now uses v_cvt_pk_bf16_f32 (8 ops/thread/chunk, was ~50).
// Pipeline unchanged from r10: reg-staged float4 loads + ds_write_b128 to the same
// linear LDS layout global_load_lds produced; 2-buffer LDS, 1 barrier/chunk,
// loads for c+2 issued at end of iteration c. wout fp32->bf16 grid-stride tail.
__global__ __launch_bounds__(256, 3)
void gemm_qkv(const float* __restrict__ A, const float* __restrict__ B,
              const float* __restrict__ Wo,
              bf16* __restrict__ outq, bf16* __restrict__ outk,
              f16* __restrict__ outv, bf16* __restrict__ woutb) {
  __shared__ __align__(16) bf16 As[2][128 * 32];   // 8 KB
  __shared__ __align__(16) bf16 Bs[2][128 * 32];   // 8 KB
  const int K = 1024;
  const int tid = threadIdx.x;
  const int w = tid >> 6;
  const int lane = tid & 63;
  const int quad = lane >> 4;
  const int col = lane & 15;
  const int waveM = w >> 1;
  const int waveN = w & 1;
  const int bm = blockIdx.y * 128;
  const int bn = blockIdx.x * 128;

  f32x4 acc[4][4] = {};
  const int srow = lane >> 2;                                  // 0..15
  const int skoff = (((lane & 3) ^ ((srow >> 1) & 3))) * 8;    // swizzled src block (elems)
  const int swq = (quad ^ ((col >> 1) & 3)) * 8;               // swizzled frag offset

  // in-flight chunk data: 8 float4 = 32 VGPRs
  float4 rA[2][2], rB[2][2];

  auto issue = [&](int k0) {
#pragma unroll
    for (int p = 0; p < 2; ++p) {
      int r = p * 64 + w * 16 + srow;
      const float4* pa = reinterpret_cast<const float4*>(A + (size_t)(bm + r) * K + k0 + skoff);
      rA[p][0] = pa[0];
      rA[p][1] = pa[1];
      const float4* pb = reinterpret_cast<const float4*>(B + (size_t)(bn + r) * K + k0 + skoff);
      rB[p][0] = pb[0];
      rB[p][1] = pb[1];
    }
  };
  // HW pack + ds_write to the exact bytes global_load_lds used to write
  auto writeLds = [&](int sb) {
#pragma unroll
    for (int p = 0; p < 2; ++p) {
      uint4 ua, ub;
      ua.x = cvtpk_bf16(rA[p][0].x, rA[p][0].y);
      ua.y = cvtpk_bf16(rA[p][0].z, rA[p][0].w);
      ua.z = cvtpk_bf16(rA[p][1].x, rA[p][1].y);
      ua.w = cvtpk_bf16(rA[p][1].z, rA[p][1].w);
      *reinterpret_cast<uint4*>((char*)As + sb * 8192 + p * 4096 + w * 1024 + lane * 16) = ua;
      ub.x = cvtpk_bf16(rB[p][0].x, rB[p][0].y);
      ub.y = cvtpk_bf16(rB[p][0].z, rB[p][0].w);
      ub.z = cvtpk_bf16(rB[p][1].x, rB[p][1].y);
      ub.w = cvtpk_bf16(rB[p][1].z, rB[p][1].w);
      *reinterpret_cast<uint4*>((char*)Bs + sb * 8192 + p * 4096 + w * 1024 + lane * 16) = ub;
    }
  };

  // prologue: chunk0 -> LDS buf0; chunk1 loads left in flight in regs.
  issue(0);
  writeLds(0);
  issue(32);

  int cb = 0;
  for (int k0 = 0; k0 < K; k0 += 32) {
    // my prior ds_writes must be visible to all waves past this barrier
    __asm__ volatile("s_waitcnt lgkmcnt(0)" ::: "memory");
    __asm__ volatile("s_barrier" ::: "memory");

    const bf16* at = &As[cb][0];
    const bf16* bt = &Bs[cb][0];
    bf16x8 af[4], bfr[4];
#pragma unroll
    for (int i = 0; i < 4; ++i)
      af[i] = *reinterpret_cast<const bf16x8*>(at + (waveM * 64 + i * 16 + col) * 32 + swq);
#pragma unroll
    for (int j = 0; j < 4; ++j)
      bfr[j] = *reinterpret_cast<const bf16x8*>(bt + (waveN * 64 + j * 16 + col) * 32 + swq);
#pragma unroll
    for (int i = 0; i < 4; ++i)
#pragma unroll
      for (int j = 0; j < 4; ++j)
        acc[i][j] = MFMA_BF(af[i], bfr[j], acc[i][j]);

    if (k0 + 32 < K) {
      // regs hold chunk k0+32 (issued last iteration); write into the buffer
      // chunk k0-32 used -- all waves finished reading it before the barrier.
      writeLds(cb ^ 1);
      if (k0 + 64 < K) issue(k0 + 64);
    }
    cb ^= 1;
  }

  if (bn < 2048) {
    // ---- fused RoPE + store [bh][t][d]; q scaled by 0.125*log2e ----
    const float NEGK = -0.4152410118f;  // -log2(10000)/32
    const float C1 = 0.1803368799f;     // 0.125 * log2(e)
    const float sgn = (col & 1) ? 1.0f : -1.0f;
#pragma unroll
    for (int j = 0; j < 4; ++j) {
      const int n0 = bn + waveN * 64 + j * 16;
      const int sel = n0 >> 10;                 // 0=q, 1=k
      const int hh = (n0 & 1023) >> 6;
      const int dd = (n0 & 63) + col;
      bf16* outp = sel ? outk : outq;
      const float post = sel ? 1.0f : C1;
      const float invf = __builtin_amdgcn_exp2f((float)((n0 & 31) + col) * NEGK);
#pragma unroll
      for (int i = 0; i < 4; ++i) {
#pragma unroll
        for (int r = 0; r < 4; ++r) {
          int m = bm + waveM * 64 + i * 16 + quad * 4 + r;
          int b = m >> 11, t = m & 2047;
          float v = acc[i][j][r];
          float partner = __shfl_xor(v, 1);
          float ang = (float)t * invf;
          float res = (v * __cosf(ang) + sgn * partner * __sinf(ang)) * post;
          outp[((size_t)(b * 16 + hh) * 2048 + t) * 64 + dd] = __float2bfloat16(res);
        }
      }
    }
  } else {
    // ---- V region: acc rows are t-consecutive -> pack 4 t's into b64 stores ----
    const int b = bm >> 11;
    const int tt0 = (bm & 2047) + waveM * 64;
#pragma unroll
    for (int j = 0; j < 4; ++j) {
      const int n0 = bn + waveN * 64 + j * 16;
      const int hh = (n0 & 1023) >> 6;
      const int dd = (n0 & 63) + col;
      f16* dst = outv + (size_t)(b * 16 + hh) * 131072 + (size_t)dd * 2048;
#pragma unroll
      for (int i = 0; i < 4; ++i) {
        uint2 pk;
        pk.x = __builtin_bit_cast(unsigned, __builtin_amdgcn_cvt_pkrtz(acc[i][j][0], acc[i][j][1]));
        pk.y = __builtin_bit_cast(unsigned, __builtin_amdgcn_cvt_pkrtz(acc[i][j][2], acc[i][j][3]));
        *reinterpret_cast<uint2*>(dst + tt0 + i * 16 + quad * 4) = pk;
      }
    }
  }

  // ---- wout fp32->bf16 tail (replaces the rest of cvt_all): 262144 float4s ----
  {
    int gid = (blockIdx.y * gridDim.x + blockIdx.x) * 256 + tid;   // 0..196607
    for (int i = gid; i < 262144; i += 196608) {
      float4 v = reinterpret_cast<const float4*>(Wo)[i];
      uint2 u;
      u.x = cvtpk_bf16(v.x, v.y);
      u.y = cvtpk_bf16(v.z, v.w);
      reinterpret_cast<uint2*>(woutb)[i] = u;
    }
  }
}

// ---------------- output GEMM: out[4096,1024] = y[4096,1024] * Wout^T ----------------
// FROZEN (r6-measured): 128x128 tile, 512 threads / 8 waves, grid (8,32) = 1 block/CU.
__global__ __launch_bounds__(512, 2)
void gemm_out(const bf16* __restrict__ A, const bf16* __restrict__ B,
              float* __restrict__ outf) {
  __shared__ __align__(16) bf16 As[3][128 * 32];
  __shared__ __align__(16) bf16 Bs[3][128 * 32];
  const int K = 1024;
  const int tid = threadIdx.x;
  const int w = tid >> 6;          // 0..7
  const int lane = tid & 63;
  const int quad = lane >> 4;
  const int col = lane & 15;
  const int waveM = w >> 2;
  const int waveN = w & 3;
  const int bm = blockIdx.y * 128;
  const int bn = blockIdx.x * 128;

  f32x4 acc[4][2] = {};
  const int srow = lane >> 2;
  const int skoff = (((lane & 3) ^ ((srow >> 1) & 3))) * 8;
  const int swq = (quad ^ ((col >> 1) & 3)) * 8;

  auto stage = [&](int k0, int sb) {
    int r = w * 16 + srow;
    load_lds16(A + (size_t)(bm + r) * K + k0 + skoff,
               (char*)As + sb * 8192 + w * 1024);
    load_lds16(B + (size_t)(bn + r) * K + k0 + skoff,
               (char*)Bs + sb * 8192 + w * 1024);
  };

  stage(0, 0);
  stage(32, 1);

  int cb = 0;
  for (int k0 = 0; k0 < K; k0 += 32) {
    if (k0 + 32 < K) __asm__ volatile("s_waitcnt vmcnt(2)" ::: "memory");
    else             __asm__ volatile("s_waitcnt vmcnt(0)" ::: "memory");
    __asm__ volatile("s_barrier" ::: "memory");
    if (k0 + 64 < K) {
      int nb = cb + 2; if (nb >= 3) nb -= 3;
      stage(k0 + 64, nb);
    }
    const bf16* at = &As[cb][0];
    const bf16* bt = &Bs[cb][0];
    bf16x8 af[4], bfr[2];
#pragma unroll
    for (int i = 0; i < 4; ++i)
      af[i] = *reinterpret_cast<const bf16x8*>(at + (waveM * 64 + i * 16 + col) * 32 + swq);
#pragma unroll
    for (int j = 0; j < 2; ++j)
      bfr[j] = *reinterpret_cast<const bf16x8*>(bt + (waveN * 32 + j * 16 + col) * 32 + swq);
#pragma unroll
    for (int i = 0; i < 4; ++i)
#pragma unroll
      for (int j = 0; j < 2; ++j)
        acc[i][j] = MFMA_BF(af[i], bfr[j], acc[i][j]);
    cb = (cb == 2) ? 0 : cb + 1;
  }

#pragma unroll
  for (int i = 0; i < 4; ++i)
#pragma unroll
    for (int j = 0; j < 2; ++j) {
      const int n0 = bn + waveN * 32 + j * 16;
#pragma unroll
      for (int r = 0; r < 4; ++r) {
        int m = bm + waveM * 64 + i * 16 + quad * 4 + r;
        outf[(size_t)m * 1024 + n0 + col] = acc[i][j][r];
      }
    }
}

// ---------------- flash attention: KVBLK=128, halved sync density ----------------
// FROZEN (r9-measured, 43.8us): 128-key chunks as two 64-key sub-tiles, 1 sync per
// 128 keys, 80KB LDS = 2 blocks/CU, PV lags S by one chunk, XCD = bh%8 locality.
__global__ __launch_bounds__(256, 2)
void attn_kernel(const bf16* __restrict__ qh, const bf16* __restrict__ kh,
                 const f16* __restrict__ vt, bf16* __restrict__ y) {
  __shared__ __align__(16) bf16 Ks[2][2 * 64 * 64];   // 32 KB
  __shared__ __align__(16) f16 Vs[3][2 * 64 * 64];    // 48 KB

  const int bh = blockIdx.x;          // XCD = bh % 8
  const int qt = blockIdx.y;
  const int w = threadIdx.x >> 6;
  const int lane = threadIdx.x & 63;
  const int quad = lane >> 4;
  const int col = lane & 15;

  const int qrow0 = qt * 128 + w * 32 + col;
  bf16x8 qf[2][2];
#pragma unroll
  for (int f = 0; f < 2; ++f)
#pragma unroll
    for (int c = 0; c < 2; ++c)
      qf[f][c] = *reinterpret_cast<const bf16x8*>(
          qh + ((size_t)bh * 2048 + qrow0 + f * 16) * 64 + c * 32 + quad * 8);

  const int s8 = lane >> 3;
  const int blk = (lane & 7) ^ s8;
  const bf16* kg = kh + (size_t)bh * 2048 * 64;
  const f16* vg = vt + (size_t)bh * 64 * 2048;
  // kappa permutation for LDS row p = w*16 + 8L + s8 (per 64-key sub-tile)
  const int ks0 = 32 * (w >> 1) + 8 * ((4 * w + (s8 >> 2)) & 3) + 4 * (w & 1) + (s8 & 3);
  const int ks1 = 32 * (w >> 1) + 8 * ((4 * w + 2 + (s8 >> 2)) & 3) + 4 * (w & 1) + (s8 & 3);
  const int vrow0 = w * 16 + s8;   // V rows = d, identity keys

  const int csw = col & 7;
  const int sw0 = (quad ^ csw) * 8;
  const int sw1 = ((quad + 4) ^ csw) * 8;
  const int rdbase = col * 64;

  f32x4 O[2][4] = {};
  float l[2] = {};
  f16x8 pf[2][4];      // P fragments of the PREVIOUS 128-key chunk

  auto stageK2 = [&](int kn, int kb) {
    char* kbp = (char*)Ks + kb * 16384 + w * 2048;
    load_lds16(kg + (size_t)(kn + ks0) * 64 + blk * 8, kbp);
    load_lds16(kg + (size_t)(kn + ks1) * 64 + blk * 8, kbp + 1024);
    load_lds16(kg + (size_t)(kn + 64 + ks0) * 64 + blk * 8, kbp + 8192);
    load_lds16(kg + (size_t)(kn + 64 + ks1) * 64 + blk * 8, kbp + 8192 + 1024);
  };
  auto stageV2 = [&](int kn, int vb) {
    char* vbp = (char*)Vs + vb * 16384 + w * 2048;
    load_lds16(vg + (size_t)vrow0 * 2048 + kn + blk * 8, vbp);
    load_lds16(vg + (size_t)(vrow0 + 8) * 2048 + kn + blk * 8, vbp + 1024);
    load_lds16(vg + (size_t)vrow0 * 2048 + kn + 64 + blk * 8, vbp + 8192);
    load_lds16(vg + (size_t)(vrow0 + 8) * 2048 + kn + 64 + blk * 8, vbp + 8192 + 1024);
  };

  auto softmax = [&](f32x4 (&s)[2][2][4]) {
#pragma unroll
    for (int f = 0; f < 2; ++f) {
      unsigned pk[16];
      float lf = 0.0f;
#pragma unroll
      for (int u = 0; u < 2; ++u)
#pragma unroll
        for (int t = 0; t < 4; ++t) {
          float p0 = __builtin_amdgcn_exp2f(s[f][u][t][0]);
          float p1 = __builtin_amdgcn_exp2f(s[f][u][t][1]);
          float p2 = __builtin_amdgcn_exp2f(s[f][u][t][2]);
          float p3 = __builtin_amdgcn_exp2f(s[f][u][t][3]);
          lf += (p0 + p1) + (p2 + p3);
          pk[u * 8 + t * 2]     = __builtin_bit_cast(unsigned, __builtin_amdgcn_cvt_pkrtz(p0, p1));
          pk[u * 8 + t * 2 + 1] = __builtin_bit_cast(unsigned, __builtin_amdgcn_cvt_pkrtz(p2, p3));
        }
      l[f] += lf;
      pf[f][0] = __builtin_bit_cast(f16x8, (u32x4){pk[0], pk[1], pk[2], pk[3]});
      pf[f][1] = __builtin_bit_cast(f16x8, (u32x4){pk[4], pk[5], pk[6], pk[7]});
      pf[f][2] = __builtin_bit_cast(f16x8, (u32x4){pk[8], pk[9], pk[10], pk[11]});
      pf[f][3] = __builtin_bit_cast(f16x8, (u32x4){pk[12], pk[13], pk[14], pk[15]});
    }
  };

  // ---- prologue: chunk 0 staged; peeled iteration 0 (S + softmax only) ----
  stageK2(0, 0);
  stageV2(0, 0);

  __asm__ volatile("s_waitcnt vmcnt(4)" ::: "memory");   // K(0) done, V(0) x4 in flight
  __asm__ volatile("s_barrier" ::: "memory");
  stageK2(128, 1);
  stageV2(128, 1);
  {
    f32x4 s[2][2][4];
    __builtin_amdgcn_s_setprio(1);
#pragma unroll
    for (int u = 0; u < 2; ++u) {
      const bf16* kt = &Ks[0][u * 4096];
#pragma unroll
      for (int t = 0; t < 4; ++t) {
        bf16x8 kf0 = *reinterpret_cast<const bf16x8*>(kt + t * 1024 + rdbase + sw0);
        bf16x8 kf1 = *reinterpret_cast<const bf16x8*>(kt + t * 1024 + rdbase + sw1);
#pragma unroll
        for (int f = 0; f < 2; ++f) {
          f32x4 a = {};
          a = MFMA_BF(kf0, qf[f][0], a);
          a = MFMA_BF(kf1, qf[f][1], a);
          s[f][u][t] = a;
        }
      }
    }
    __builtin_amdgcn_s_setprio(0);
    softmax(s);
  }

  // ---- main loop c = 1..15: S(c) + PV(c-1) fused MFMA cluster, 1 sync/128 keys ----
  int vprev = 0;
  int vnext = 2;
#pragma unroll 1
  for (int c = 1; c < 16; ++c) {
    const int kc = c * 128;
    __asm__ volatile("s_waitcnt vmcnt(4)" ::: "memory");
    __asm__ volatile("s_barrier" ::: "memory");
    if (c + 1 < 16) {
      stageK2(kc + 128, (c + 1) & 1);
      stageV2(kc + 128, vnext);
    }

    f32x4 s[2][2][4];
    __builtin_amdgcn_s_setprio(1);
#pragma unroll
    for (int u = 0; u < 2; ++u) {
      const bf16* kt = &Ks[c & 1][u * 4096];
      const f16* vtile = &Vs[vprev][u * 4096];
#pragma unroll
      for (int t = 0; t < 4; ++t) {
        bf16x8 kf0 = *reinterpret_cast<const bf16x8*>(kt + t * 1024 + rdbase + sw0);
        bf16x8 kf1 = *reinterpret_cast<const bf16x8*>(kt + t * 1024 + rdbase + sw1);
        f16x8 vf0 = *reinterpret_cast<const f16x8*>(vtile + t * 1024 + rdbase + sw0);
        f16x8 vf1 = *reinterpret_cast<const f16x8*>(vtile + t * 1024 + rdbase + sw1);
#pragma unroll
        for (int f = 0; f < 2; ++f) {
          f32x4 a = {};
          a = MFMA_BF(kf0, qf[f][0], a);
          a = MFMA_BF(kf1, qf[f][1], a);
          s[f][u][t] = a;
          O[f][t] = MFMA_F16(vf0, pf[f][u * 2], O[f][t]);
          O[f][t] = MFMA_F16(vf1, pf[f][u * 2 + 1], O[f][t]);
        }
      }
    }
    __builtin_amdgcn_s_setprio(0);
    softmax(s);

    vprev = (vprev == 2) ? 0 : vprev + 1;
    vnext = (vnext == 2) ? 0 : vnext + 1;
  }

  // ---- epilogue: final PV for chunk 15 ----
  __asm__ volatile("s_waitcnt vmcnt(0)" ::: "memory");
  __asm__ volatile("s_barrier" ::: "memory");
  {
    __builtin_amdgcn_s_setprio(1);
#pragma unroll
    for (int u = 0; u < 2; ++u) {
      const f16* vtile = &Vs[vprev][u * 4096];
#pragma unroll
      for (int t = 0; t < 4; ++t) {
        f16x8 vf0 = *reinterpret_cast<const f16x8*>(vtile + t * 1024 + rdbase + sw0);
        f16x8 vf1 = *reinterpret_cast<const f16x8*>(vtile + t * 1024 + rdbase + sw1);
#pragma unroll
        for (int f = 0; f < 2; ++f) {
          O[f][t] = MFMA_F16(vf0, pf[f][u * 2], O[f][t]);
          O[f][t] = MFMA_F16(vf1, pf[f][u * 2 + 1], O[f][t]);
        }
      }
    }
    __builtin_amdgcn_s_setprio(0);
  }

  // ---- reduce l over quads, normalize, direct y write ----
  const int b = bh >> 4, h = bh & 15;
#pragma unroll
  for (int f = 0; f < 2; ++f) {
    float lv = l[f];
    lv += __shfl_xor(lv, 16, 64);
    lv += __shfl_xor(lv, 32, 64);
    float inv = 1.0f / lv;
    int tq = qt * 128 + w * 32 + f * 16 + col;
    size_t base = ((size_t)b * 2048 + tq) * 1024 + h * 64;
#pragma unroll
    for (int j = 0; j < 4; ++j) {
      uint2 pk2;
      pk2.x = pk_bf16(O[f][j][0] * inv, O[f][j][1] * inv);
      pk2.y = pk_bf16(O[f][j][2] * inv, O[f][j][3] * inv);
      *reinterpret_cast<uint2*>((unsigned short*)y + base + j * 16 + quad * 4) = pk2;
    }
  }
}

extern "C" void kernel_launch(void* const* d_in, const int* in_sizes, int n_in,
                              void* d_out, int out_size, void* d_ws, size_t ws_size,
                              hipStream_t stream) {
  const float* x    = (const float*)d_in[0];
  const float* wqkv = (const float*)d_in[1];
  const float* wout = (const float*)d_in[2];
  float* out = (float*)d_out;
  char* ws = (char*)d_ws;

  bf16* woutb = (bf16*)(ws);                        // 2 MB
  bf16* qh    = (bf16*)(ws + (size_t)(2 << 20));    // 8 MB
  bf16* kh    = (bf16*)(ws + (size_t)(10 << 20));   // 8 MB
  f16*  vt    = (f16*) (ws + (size_t)(18 << 20));   // 8 MB
  bf16* y     = (bf16*)(ws + (size_t)(26 << 20));   // 8 MB  (total 34 MB)

  gemm_qkv<<<dim3(24, 32), 256, 0, stream>>>(x, wqkv, wout, qh, kh, vt, woutb);
  attn_kernel<<<dim3(32, 16), 256, 0, stream>>>(qh, kh, vt, y);
  gemm_out<<<dim3(8, 32), 512, 0, stream>>>(y, woutb, out);
}

// Round 12
// 172.946 us; speedup vs baseline: 1.0593x; 1.0177x over previous
//
#include <hip/hip_runtime.h>
#include <hip/hip_bf16.h>
#include <math.h>

typedef __hip_bfloat16 bf16;
typedef _Float16 f16;
typedef __attribute__((ext_vector_type(8))) short bf16x8;
typedef __attribute__((ext_vector_type(8))) _Float16 f16x8;
typedef __attribute__((ext_vector_type(4))) float f32x4;
typedef __attribute__((ext_vector_type(4))) unsigned u32x4;

#define MFMA_BF(a,b,c) __builtin_amdgcn_mfma_f32_16x16x32_bf16((a),(b),(c),0,0,0)
#define MFMA_F16(a,b,c) __builtin_amdgcn_mfma_f32_16x16x32_f16((a),(b),(c),0,0,0)

__device__ __forceinline__ void load_lds16(const void* g, void* l) {
  __builtin_amdgcn_global_load_lds(
      (__attribute__((address_space(1))) void*)(g),
      (__attribute__((address_space(3))) void*)(l), 16, 0, 0);
}

// RTNE f32->bf16 pair pack (software; epilogue use)
__device__ __forceinline__ unsigned pk_bf16(float a, float b) {
  unsigned ua = __builtin_bit_cast(unsigned, a);
  unsigned ub = __builtin_bit_cast(unsigned, b);
  ua += 0x7fffu + ((ua >> 16) & 1u);
  ub += 0x7fffu + ((ub >> 16) & 1u);
  return (ua >> 16) | (ub & 0xffff0000u);
}

// HW RTNE f32-pair -> packed bf16 (1 VALU op; verified r11 -- numerics identical)
__device__ __forceinline__ unsigned cvtpk_bf16(float a, float b) {
  unsigned r;
  __asm__("v_cvt_pk_bf16_f32 %0, %1, %2" : "=v"(r) : "v"(a), "v"(b));
  return r;
}

// ---------------- fused fp32 -> bf16 convert (x, W_qkv, W_out) ----------------
// RESTORED (r12): budget re-fit across r9-r11 shows launch gaps ~0 under graph
// capture (a 44.6us harness fillBuffer sits inside the timed window) -- the r10/r11
// "save a launch" fusion had no gap to save, and fused qkv (57.6us, latency-bound
// at 16% Mfma) strictly loses to cvt(8) + r9-form qkv (~42). BW-bound kernel.
__global__ void cvt_all(const float* __restrict__ x, const float* __restrict__ wq,
                        const float* __restrict__ wo, unsigned* __restrict__ xb,
                        unsigned* __restrict__ wqb, unsigned* __restrict__ wob) {
  int i = blockIdx.x * blockDim.x + threadIdx.x;  // float4 index, 2097152 total
  const float* src;
  unsigned* dst;
  int off;
  if (i < 1048576) { src = x; dst = xb; off = i; }
  else if (i < 1048576 + 786432) { src = wq; dst = wqb; off = i - 1048576; }
  else { src = wo; dst = wob; off = i - (1048576 + 786432); }
  float4 v = reinterpret_cast<const float4*>(src)[off];
  uint2 u;
  u.x = cvtpk_bf16(v.x, v.y);
  u.y = cvtpk_bf16(v.z, v.w);
  reinterpret_cast<uint2*>(dst)[off] = u;
}

// ---------------- merged QKV GEMM: C[M,3072] = A[M,1024] * Wqkv^T ----------------
// RESTORED to r9-measured form (~42us): 3-deep global_load_lds pipeline, partial
// vmcnt waits, XOR-swizzled staging, (256,3) = 768 blocks all resident.
__global__ __launch_bounds__(256, 3)
void gemm_qkv(const bf16* __restrict__ A, const bf16* __restrict__ B,
              bf16* __restrict__ outq, bf16* __restrict__ outk,
              f16* __restrict__ outv) {
  __shared__ __align__(16) bf16 As[3][128 * 32];
  __shared__ __align__(16) bf16 Bs[3][128 * 32];
  const int K = 1024;
  const int tid = threadIdx.x;
  const int w = tid >> 6;
  const int lane = tid & 63;
  const int quad = lane >> 4;
  const int col = lane & 15;
  const int waveM = w >> 1;
  const int waveN = w & 1;
  const int bm = blockIdx.y * 128;
  const int bn = blockIdx.x * 128;

  f32x4 acc[4][4] = {};
  const int srow = lane >> 2;                                  // 0..15
  const int skoff = (((lane & 3) ^ ((srow >> 1) & 3))) * 8;    // swizzled src block
  const int swq = (quad ^ ((col >> 1) & 3)) * 8;               // swizzled frag offset

  auto stage = [&](int k0, int sb) {
#pragma unroll
    for (int p = 0; p < 2; ++p) {
      int r = p * 64 + w * 16 + srow;
      load_lds16(A + (size_t)(bm + r) * K + k0 + skoff,
                 (char*)As + sb * 8192 + p * 4096 + w * 1024);
      load_lds16(B + (size_t)(bn + r) * K + k0 + skoff,
                 (char*)Bs + sb * 8192 + p * 4096 + w * 1024);
    }
  };

  stage(0, 0);
  stage(32, 1);

  int cb = 0;
  for (int k0 = 0; k0 < K; k0 += 32) {
    if (k0 + 32 < K) __asm__ volatile("s_waitcnt vmcnt(4)" ::: "memory");
    else             __asm__ volatile("s_waitcnt vmcnt(0)" ::: "memory");
    __asm__ volatile("s_barrier" ::: "memory");
    if (k0 + 64 < K) {
      int nb = cb + 2; if (nb >= 3) nb -= 3;
      stage(k0 + 64, nb);
    }
    const bf16* at = &As[cb][0];
    const bf16* bt = &Bs[cb][0];
    bf16x8 af[4], bfr[4];
#pragma unroll
    for (int i = 0; i < 4; ++i)
      af[i] = *reinterpret_cast<const bf16x8*>(at + (waveM * 64 + i * 16 + col) * 32 + swq);
#pragma unroll
    for (int j = 0; j < 4; ++j)
      bfr[j] = *reinterpret_cast<const bf16x8*>(bt + (waveN * 64 + j * 16 + col) * 32 + swq);
#pragma unroll
    for (int i = 0; i < 4; ++i)
#pragma unroll
      for (int j = 0; j < 4; ++j)
        acc[i][j] = MFMA_BF(af[i], bfr[j], acc[i][j]);
    cb = (cb == 2) ? 0 : cb + 1;
  }

  if (bn < 2048) {
    // ---- fused RoPE + store [bh][t][d]; q scaled by 0.125*log2e ----
    const float NEGK = -0.4152410118f;  // -log2(10000)/32
    const float C1 = 0.1803368799f;     // 0.125 * log2(e)
    const float sgn = (col & 1) ? 1.0f : -1.0f;
#pragma unroll
    for (int j = 0; j < 4; ++j) {
      const int n0 = bn + waveN * 64 + j * 16;
      const int sel = n0 >> 10;                 // 0=q, 1=k
      const int hh = (n0 & 1023) >> 6;
      const int dd = (n0 & 63) + col;
      bf16* outp = sel ? outk : outq;
      const float post = sel ? 1.0f : C1;
      const float invf = __builtin_amdgcn_exp2f((float)((n0 & 31) + col) * NEGK);
#pragma unroll
      for (int i = 0; i < 4; ++i) {
#pragma unroll
        for (int r = 0; r < 4; ++r) {
          int m = bm + waveM * 64 + i * 16 + quad * 4 + r;
          int b = m >> 11, t = m & 2047;
          float v = acc[i][j][r];
          float partner = __shfl_xor(v, 1);
          float ang = (float)t * invf;
          float res = (v * __cosf(ang) + sgn * partner * __sinf(ang)) * post;
          outp[((size_t)(b * 16 + hh) * 2048 + t) * 64 + dd] = __float2bfloat16(res);
        }
      }
    }
  } else {
    // ---- V region: acc rows are t-consecutive -> pack 4 t's into b64 stores ----
    const int b = bm >> 11;
    const int tt0 = (bm & 2047) + waveM * 64;
#pragma unroll
    for (int j = 0; j < 4; ++j) {
      const int n0 = bn + waveN * 64 + j * 16;
      const int hh = (n0 & 1023) >> 6;
      const int dd = (n0 & 63) + col;
      f16* dst = outv + (size_t)(b * 16 + hh) * 131072 + (size_t)dd * 2048;
#pragma unroll
      for (int i = 0; i < 4; ++i) {
        uint2 pk;
        pk.x = __builtin_bit_cast(unsigned, __builtin_amdgcn_cvt_pkrtz(acc[i][j][0], acc[i][j][1]));
        pk.y = __builtin_bit_cast(unsigned, __builtin_amdgcn_cvt_pkrtz(acc[i][j][2], acc[i][j][3]));
        *reinterpret_cast<uint2*>(dst + tt0 + i * 16 + quad * 4) = pk;
      }
    }
  }
}

// ---------------- output GEMM: out[4096,1024] = y[4096,1024] * Wout^T ----------------
// ROUND 12 REBUILD. Inferred ~30-36us at 256 blocks = 1 block/CU (8 barrier-ganged
// waves, latency-exposed; never directly profiled -- always below top-5 threshold).
// Cure proven by qkv_r9: small INDEPENDENT blocks, >=3/CU. 64x64 tiles -> grid
// (16,64) = 1024 blocks = exactly 4 blocks/CU ((256,4); LDS 24KB x 4 = 96KB).
// 16 waves/CU, stalls decorrelated across 4 blocks. Same 3-deep global_load_lds
// pipeline / swizzle / vmcnt discipline as the proven kernels. Wave = 32x32
// sub-tile (acc[2][2], af[2], bfr[2], 4 MFMA/iter).
__global__ __launch_bounds__(256, 4)
void gemm_out(const bf16* __restrict__ A, const bf16* __restrict__ B,
              float* __restrict__ outf) {
  __shared__ __align__(16) bf16 As[3][64 * 32];   // 12 KB
  __shared__ __align__(16) bf16 Bs[3][64 * 32];   // 12 KB
  const int K = 1024;
  const int tid = threadIdx.x;
  const int w = tid >> 6;
  const int lane = tid & 63;
  const int quad = lane >> 4;
  const int col = lane & 15;
  const int waveM = w >> 1;        // 0..1 -> 32-row half
  const int waveN = w & 1;         // 0..1 -> 32-col half
  const int bm = blockIdx.y * 64;
  const int bn = blockIdx.x * 64;

  f32x4 acc[2][2] = {};
  const int srow = lane >> 2;
  const int skoff = (((lane & 3) ^ ((srow >> 1) & 3))) * 8;
  const int swq = (quad ^ ((col >> 1) & 3)) * 8;

  // 4 waves x 16 rows = 64 rows; one 16B load per lane per matrix per chunk
  auto stage = [&](int k0, int sb) {
    int r = w * 16 + srow;
    load_lds16(A + (size_t)(bm + r) * K + k0 + skoff,
               (char*)As + sb * 4096 + w * 1024);
    load_lds16(B + (size_t)(bn + r) * K + k0 + skoff,
               (char*)Bs + sb * 4096 + w * 1024);
  };

  stage(0, 0);
  stage(32, 1);

  int cb = 0;
  for (int k0 = 0; k0 < K; k0 += 32) {
    // per-wave outstanding: chunk k (2, oldest) + chunk k+1 (2) -> wait to 2
    if (k0 + 32 < K) __asm__ volatile("s_waitcnt vmcnt(2)" ::: "memory");
    else             __asm__ volatile("s_waitcnt vmcnt(0)" ::: "memory");
    __asm__ volatile("s_barrier" ::: "memory");
    if (k0 + 64 < K) {
      int nb = cb + 2; if (nb >= 3) nb -= 3;
      stage(k0 + 64, nb);
    }
    const bf16* at = &As[cb][0];
    const bf16* bt = &Bs[cb][0];
    bf16x8 af[2], bfr[2];
#pragma unroll
    for (int i = 0; i < 2; ++i)
      af[i] = *reinterpret_cast<const bf16x8*>(at + (waveM * 32 + i * 16 + col) * 32 + swq);
#pragma unroll
    for (int j = 0; j < 2; ++j)
      bfr[j] = *reinterpret_cast<const bf16x8*>(bt + (waveN * 32 + j * 16 + col) * 32 + swq);
#pragma unroll
    for (int i = 0; i < 2; ++i)
#pragma unroll
      for (int j = 0; j < 2; ++j)
        acc[i][j] = MFMA_BF(af[i], bfr[j], acc[i][j]);
    cb = (cb == 2) ? 0 : cb + 1;
  }

#pragma unroll
  for (int i = 0; i < 2; ++i)
#pragma unroll
    for (int j = 0; j < 2; ++j) {
      const int n0 = bn + waveN * 32 + j * 16;
#pragma unroll
      for (int r = 0; r < 4; ++r) {
        int m = bm + waveM * 32 + i * 16 + quad * 4 + r;
        outf[(size_t)m * 1024 + n0 + col] = acc[i][j][r];
      }
    }
}

// ---------------- flash attention: KVBLK=128, halved sync density ----------------
// FROZEN (r9-measured, 43.8us): 128-key chunks as two 64-key sub-tiles, 1 sync per
// 128 keys, 80KB LDS = 2 blocks/CU, PV lags S by one chunk, XCD = bh%8 locality.
__global__ __launch_bounds__(256, 2)
void attn_kernel(const bf16* __restrict__ qh, const bf16* __restrict__ kh,
                 const f16* __restrict__ vt, bf16* __restrict__ y) {
  __shared__ __align__(16) bf16 Ks[2][2 * 64 * 64];   // 32 KB
  __shared__ __align__(16) f16 Vs[3][2 * 64 * 64];    // 48 KB

  const int bh = blockIdx.x;          // XCD = bh % 8
  const int qt = blockIdx.y;
  const int w = threadIdx.x >> 6;
  const int lane = threadIdx.x & 63;
  const int quad = lane >> 4;
  const int col = lane & 15;

  const int qrow0 = qt * 128 + w * 32 + col;
  bf16x8 qf[2][2];
#pragma unroll
  for (int f = 0; f < 2; ++f)
#pragma unroll
    for (int c = 0; c < 2; ++c)
      qf[f][c] = *reinterpret_cast<const bf16x8*>(
          qh + ((size_t)bh * 2048 + qrow0 + f * 16) * 64 + c * 32 + quad * 8);

  const int s8 = lane >> 3;
  const int blk = (lane & 7) ^ s8;
  const bf16* kg = kh + (size_t)bh * 2048 * 64;
  const f16* vg = vt + (size_t)bh * 64 * 2048;
  // kappa permutation for LDS row p = w*16 + 8L + s8 (per 64-key sub-tile)
  const int ks0 = 32 * (w >> 1) + 8 * ((4 * w + (s8 >> 2)) & 3) + 4 * (w & 1) + (s8 & 3);
  const int ks1 = 32 * (w >> 1) + 8 * ((4 * w + 2 + (s8 >> 2)) & 3) + 4 * (w & 1) + (s8 & 3);
  const int vrow0 = w * 16 + s8;   // V rows = d, identity keys

  const int csw = col & 7;
  const int sw0 = (quad ^ csw) * 8;
  const int sw1 = ((quad + 4) ^ csw) * 8;
  const int rdbase = col * 64;

  f32x4 O[2][4] = {};
  float l[2] = {};
  f16x8 pf[2][4];      // P fragments of the PREVIOUS 128-key chunk

  auto stageK2 = [&](int kn, int kb) {
    char* kbp = (char*)Ks + kb * 16384 + w * 2048;
    load_lds16(kg + (size_t)(kn + ks0) * 64 + blk * 8, kbp);
    load_lds16(kg + (size_t)(kn + ks1) * 64 + blk * 8, kbp + 1024);
    load_lds16(kg + (size_t)(kn + 64 + ks0) * 64 + blk * 8, kbp + 8192);
    load_lds16(kg + (size_t)(kn + 64 + ks1) * 64 + blk * 8, kbp + 8192 + 1024);
  };
  auto stageV2 = [&](int kn, int vb) {
    char* vbp = (char*)Vs + vb * 16384 + w * 2048;
    load_lds16(vg + (size_t)vrow0 * 2048 + kn + blk * 8, vbp);
    load_lds16(vg + (size_t)(vrow0 + 8) * 2048 + kn + blk * 8, vbp + 1024);
    load_lds16(vg + (size_t)vrow0 * 2048 + kn + 64 + blk * 8, vbp + 8192);
    load_lds16(vg + (size_t)(vrow0 + 8) * 2048 + kn + 64 + blk * 8, vbp + 8192 + 1024);
  };

  auto softmax = [&](f32x4 (&s)[2][2][4]) {
#pragma unroll
    for (int f = 0; f < 2; ++f) {
      unsigned pk[16];
      float lf = 0.0f;
#pragma unroll
      for (int u = 0; u < 2; ++u)
#pragma unroll
        for (int t = 0; t < 4; ++t) {
          float p0 = __builtin_amdgcn_exp2f(s[f][u][t][0]);
          float p1 = __builtin_amdgcn_exp2f(s[f][u][t][1]);
          float p2 = __builtin_amdgcn_exp2f(s[f][u][t][2]);
          float p3 = __builtin_amdgcn_exp2f(s[f][u][t][3]);
          lf += (p0 + p1) + (p2 + p3);
          pk[u * 8 + t * 2]     = __builtin_bit_cast(unsigned, __builtin_amdgcn_cvt_pkrtz(p0, p1));
          pk[u * 8 + t * 2 + 1] = __builtin_bit_cast(unsigned, __builtin_amdgcn_cvt_pkrtz(p2, p3));
        }
      l[f] += lf;
      pf[f][0] = __builtin_bit_cast(f16x8, (u32x4){pk[0], pk[1], pk[2], pk[3]});
      pf[f][1] = __builtin_bit_cast(f16x8, (u32x4){pk[4], pk[5], pk[6], pk[7]});
      pf[f][2] = __builtin_bit_cast(f16x8, (u32x4){pk[8], pk[9], pk[10], pk[11]});
      pf[f][3] = __builtin_bit_cast(f16x8, (u32x4){pk[12], pk[13], pk[14], pk[15]});
    }
  };

  // ---- prologue: chunk 0 staged; peeled iteration 0 (S + softmax only) ----
  stageK2(0, 0);
  stageV2(0, 0);

  __asm__ volatile("s_waitcnt vmcnt(4)" ::: "memory");   // K(0) done, V(0) x4 in flight
  __asm__ volatile("s_barrier" ::: "memory");
  stageK2(128, 1);
  stageV2(128, 1);
  {
    f32x4 s[2][2][4];
    __builtin_amdgcn_s_setprio(1);
#pragma unroll
    for (int u = 0; u < 2; ++u) {
      const bf16* kt = &Ks[0][u * 4096];
#pragma unroll
      for (int t = 0; t < 4; ++t) {
        bf16x8 kf0 = *reinterpret_cast<const bf16x8*>(kt + t * 1024 + rdbase + sw0);
        bf16x8 kf1 = *reinterpret_cast<const bf16x8*>(kt + t * 1024 + rdbase + sw1);
#pragma unroll
        for (int f = 0; f < 2; ++f) {
          f32x4 a = {};
          a = MFMA_BF(kf0, qf[f][0], a);
          a = MFMA_BF(kf1, qf[f][1], a);
          s[f][u][t] = a;
        }
      }
    }
    __builtin_amdgcn_s_setprio(0);
    softmax(s);
  }

  // ---- main loop c = 1..15: S(c) + PV(c-1) fused MFMA cluster, 1 sync/128 keys ----
  int vprev = 0;
  int vnext = 2;
#pragma unroll 1
  for (int c = 1; c < 16; ++c) {
    const int kc = c * 128;
    __asm__ volatile("s_waitcnt vmcnt(4)" ::: "memory");
    __asm__ volatile("s_barrier" ::: "memory");
    if (c + 1 < 16) {
      stageK2(kc + 128, (c + 1) & 1);
      stageV2(kc + 128, vnext);
    }

    f32x4 s[2][2][4];
    __builtin_amdgcn_s_setprio(1);
#pragma unroll
    for (int u = 0; u < 2; ++u) {
      const bf16* kt = &Ks[c & 1][u * 4096];
      const f16* vtile = &Vs[vprev][u * 4096];
#pragma unroll
      for (int t = 0; t < 4; ++t) {
        bf16x8 kf0 = *reinterpret_cast<const bf16x8*>(kt + t * 1024 + rdbase + sw0);
        bf16x8 kf1 = *reinterpret_cast<const bf16x8*>(kt + t * 1024 + rdbase + sw1);
        f16x8 vf0 = *reinterpret_cast<const f16x8*>(vtile + t * 1024 + rdbase + sw0);
        f16x8 vf1 = *reinterpret_cast<const f16x8*>(vtile + t * 1024 + rdbase + sw1);
#pragma unroll
        for (int f = 0; f < 2; ++f) {
          f32x4 a = {};
          a = MFMA_BF(kf0, qf[f][0], a);
          a = MFMA_BF(kf1, qf[f][1], a);
          s[f][u][t] = a;
          O[f][t] = MFMA_F16(vf0, pf[f][u * 2], O[f][t]);
          O[f][t] = MFMA_F16(vf1, pf[f][u * 2 + 1], O[f][t]);
        }
      }
    }
    __builtin_amdgcn_s_setprio(0);
    softmax(s);

    vprev = (vprev == 2) ? 0 : vprev + 1;
    vnext = (vnext == 2) ? 0 : vnext + 1;
  }

  // ---- epilogue: final PV for chunk 15 ----
  __asm__ volatile("s_waitcnt vmcnt(0)" ::: "memory");
  __asm__ volatile("s_barrier" ::: "memory");
  {
    __builtin_amdgcn_s_setprio(1);
#pragma unroll
    for (int u = 0; u < 2; ++u) {
      const f16* vtile = &Vs[vprev][u * 4096];
#pragma unroll
      for (int t = 0; t < 4; ++t) {
        f16x8 vf0 = *reinterpret_cast<const f16x8*>(vtile + t * 1024 + rdbase + sw0);
        f16x8 vf1 = *reinterpret_cast<const f16x8*>(vtile + t * 1024 + rdbase + sw1);
#pragma unroll
        for (int f = 0; f < 2; ++f) {
          O[f][t] = MFMA_F16(vf0, pf[f][u * 2], O[f][t]);
          O[f][t] = MFMA_F16(vf1, pf[f][u * 2 + 1], O[f][t]);
        }
      }
    }
    __builtin_amdgcn_s_setprio(0);
  }

  // ---- reduce l over quads, normalize, direct y write ----
  const int b = bh >> 4, h = bh & 15;
#pragma unroll
  for (int f = 0; f < 2; ++f) {
    float lv = l[f];
    lv += __shfl_xor(lv, 16, 64);
    lv += __shfl_xor(lv, 32, 64);
    float inv = 1.0f / lv;
    int tq = qt * 128 + w * 32 + f * 16 + col;
    size_t base = ((size_t)b * 2048 + tq) * 1024 + h * 64;
#pragma unroll
    for (int j = 0; j < 4; ++j) {
      uint2 pk2;
      pk2.x = pk_bf16(O[f][j][0] * inv, O[f][j][1] * inv);
      pk2.y = pk_bf16(O[f][j][2] * inv, O[f][j][3] * inv);
      *reinterpret_cast<uint2*>((unsigned short*)y + base + j * 16 + quad * 4) = pk2;
    }
  }
}

extern "C" void kernel_launch(void* const* d_in, const int* in_sizes, int n_in,
                              void* d_out, int out_size, void* d_ws, size_t ws_size,
                              hipStream_t stream) {
  const float* x    = (const float*)d_in[0];
  const float* wqkv = (const float*)d_in[1];
  const float* wout = (const float*)d_in[2];
  float* out = (float*)d_out;
  char* ws = (char*)d_ws;

  bf16* xb    = (bf16*)(ws);                        // 8 MB (dead after gemm_qkv)
  bf16* wqkvb = (bf16*)(ws + (size_t)(8 << 20));    // 6 MB
  bf16* woutb = (bf16*)(ws + (size_t)(14 << 20));   // 2 MB
  bf16* qh    = (bf16*)(ws + (size_t)(16 << 20));   // 8 MB
  bf16* kh    = (bf16*)(ws + (size_t)(24 << 20));   // 8 MB
  f16*  vt    = (f16*) (ws + (size_t)(32 << 20));   // 8 MB
  bf16* y     = (bf16*)(ws);                        // 8 MB, overlays dead xb (40 MB)

  cvt_all<<<8192, 256, 0, stream>>>(x, wqkv, wout,
                                    (unsigned*)xb, (unsigned*)wqkvb, (unsigned*)woutb);
  gemm_qkv<<<dim3(24, 32), 256, 0, stream>>>(xb, wqkvb, qh, kh, vt);
  attn_kernel<<<dim3(32, 16), 256, 0, stream>>>(qh, kh, vt, y);
  gemm_out<<<dim3(16, 64), 256, 0, stream>>>(y, woutb, out);
}

// Round 13
// 172.123 us; speedup vs baseline: 1.0643x; 1.0048x over previous
//
#include <hip/hip_runtime.h>
#include <hip/hip_bf16.h>
#include <math.h>

typedef __hip_bfloat16 bf16;
typedef _Float16 f16;
typedef __attribute__((ext_vector_type(8))) short bf16x8;
typedef __attribute__((ext_vector_type(8))) _Float16 f16x8;
typedef __attribute__((ext_vector_type(4))) float f32x4;
typedef __attribute__((ext_vector_type(4))) unsigned u32x4;

#define MFMA_BF(a,b,c) __builtin_amdgcn_mfma_f32_16x16x32_bf16((a),(b),(c),0,0,0)
#define MFMA_F16(a,b,c) __builtin_amdgcn_mfma_f32_16x16x32_f16((a),(b),(c),0,0,0)

__device__ __forceinline__ void load_lds16(const void* g, void* l) {
  __builtin_amdgcn_global_load_lds(
      (__attribute__((address_space(1))) void*)(g),
      (__attribute__((address_space(3))) void*)(l), 16, 0, 0);
}

// RTNE f32->bf16 pair pack (software; epilogue use)
__device__ __forceinline__ unsigned pk_bf16(float a, float b) {
  unsigned ua = __builtin_bit_cast(unsigned, a);
  unsigned ub = __builtin_bit_cast(unsigned, b);
  ua += 0x7fffu + ((ua >> 16) & 1u);
  ub += 0x7fffu + ((ub >> 16) & 1u);
  return (ua >> 16) | (ub & 0xffff0000u);
}

// HW RTNE f32-pair -> packed bf16 (1 VALU op; verified r11 -- numerics identical)
__device__ __forceinline__ unsigned cvtpk_bf16(float a, float b) {
  unsigned r;
  __asm__("v_cvt_pk_bf16_f32 %0, %1, %2" : "=v"(r) : "v"(a), "v"(b));
  return r;
}

// ---------------- fused fp32 -> bf16 convert (x, W_qkv, W_out) ----------------
// FROZEN (r12-measured, ~8us, BW-bound).
__global__ void cvt_all(const float* __restrict__ x, const float* __restrict__ wq,
                        const float* __restrict__ wo, unsigned* __restrict__ xb,
                        unsigned* __restrict__ wqb, unsigned* __restrict__ wob) {
  int i = blockIdx.x * blockDim.x + threadIdx.x;  // float4 index, 2097152 total
  const float* src;
  unsigned* dst;
  int off;
  if (i < 1048576) { src = x; dst = xb; off = i; }
  else if (i < 1048576 + 786432) { src = wq; dst = wqb; off = i - 1048576; }
  else { src = wo; dst = wob; off = i - (1048576 + 786432); }
  float4 v = reinterpret_cast<const float4*>(src)[off];
  uint2 u;
  u.x = cvtpk_bf16(v.x, v.y);
  u.y = cvtpk_bf16(v.z, v.w);
  reinterpret_cast<uint2*>(dst)[off] = u;
}

// ---------------- merged QKV GEMM: C[M,3072] = A[M,1024] * Wqkv^T ----------------
// FROZEN (r9/r12-measured, ~46us): 3-deep global_load_lds pipeline, partial vmcnt,
// XOR-swizzled staging, (256,3) = 768 blocks all resident.
__global__ __launch_bounds__(256, 3)
void gemm_qkv(const bf16* __restrict__ A, const bf16* __restrict__ B,
              bf16* __restrict__ outq, bf16* __restrict__ outk,
              f16* __restrict__ outv) {
  __shared__ __align__(16) bf16 As[3][128 * 32];
  __shared__ __align__(16) bf16 Bs[3][128 * 32];
  const int K = 1024;
  const int tid = threadIdx.x;
  const int w = tid >> 6;
  const int lane = tid & 63;
  const int quad = lane >> 4;
  const int col = lane & 15;
  const int waveM = w >> 1;
  const int waveN = w & 1;
  const int bm = blockIdx.y * 128;
  const int bn = blockIdx.x * 128;

  f32x4 acc[4][4] = {};
  const int srow = lane >> 2;                                  // 0..15
  const int skoff = (((lane & 3) ^ ((srow >> 1) & 3))) * 8;    // swizzled src block
  const int swq = (quad ^ ((col >> 1) & 3)) * 8;               // swizzled frag offset

  auto stage = [&](int k0, int sb) {
#pragma unroll
    for (int p = 0; p < 2; ++p) {
      int r = p * 64 + w * 16 + srow;
      load_lds16(A + (size_t)(bm + r) * K + k0 + skoff,
                 (char*)As + sb * 8192 + p * 4096 + w * 1024);
      load_lds16(B + (size_t)(bn + r) * K + k0 + skoff,
                 (char*)Bs + sb * 8192 + p * 4096 + w * 1024);
    }
  };

  stage(0, 0);
  stage(32, 1);

  int cb = 0;
  for (int k0 = 0; k0 < K; k0 += 32) {
    if (k0 + 32 < K) __asm__ volatile("s_waitcnt vmcnt(4)" ::: "memory");
    else             __asm__ volatile("s_waitcnt vmcnt(0)" ::: "memory");
    __asm__ volatile("s_barrier" ::: "memory");
    if (k0 + 64 < K) {
      int nb = cb + 2; if (nb >= 3) nb -= 3;
      stage(k0 + 64, nb);
    }
    const bf16* at = &As[cb][0];
    const bf16* bt = &Bs[cb][0];
    bf16x8 af[4], bfr[4];
#pragma unroll
    for (int i = 0; i < 4; ++i)
      af[i] = *reinterpret_cast<const bf16x8*>(at + (waveM * 64 + i * 16 + col) * 32 + swq);
#pragma unroll
    for (int j = 0; j < 4; ++j)
      bfr[j] = *reinterpret_cast<const bf16x8*>(bt + (waveN * 64 + j * 16 + col) * 32 + swq);
#pragma unroll
    for (int i = 0; i < 4; ++i)
#pragma unroll
      for (int j = 0; j < 4; ++j)
        acc[i][j] = MFMA_BF(af[i], bfr[j], acc[i][j]);
    cb = (cb == 2) ? 0 : cb + 1;
  }

  if (bn < 2048) {
    // ---- fused RoPE + store [bh][t][d]; q scaled by 0.125*log2e ----
    const float NEGK = -0.4152410118f;  // -log2(10000)/32
    const float C1 = 0.1803368799f;     // 0.125 * log2(e)
    const float sgn = (col & 1) ? 1.0f : -1.0f;
#pragma unroll
    for (int j = 0; j < 4; ++j) {
      const int n0 = bn + waveN * 64 + j * 16;
      const int sel = n0 >> 10;                 // 0=q, 1=k
      const int hh = (n0 & 1023) >> 6;
      const int dd = (n0 & 63) + col;
      bf16* outp = sel ? outk : outq;
      const float post = sel ? 1.0f : C1;
      const float invf = __builtin_amdgcn_exp2f((float)((n0 & 31) + col) * NEGK);
#pragma unroll
      for (int i = 0; i < 4; ++i) {
#pragma unroll
        for (int r = 0; r < 4; ++r) {
          int m = bm + waveM * 64 + i * 16 + quad * 4 + r;
          int b = m >> 11, t = m & 2047;
          float v = acc[i][j][r];
          float partner = __shfl_xor(v, 1);
          float ang = (float)t * invf;
          float res = (v * __cosf(ang) + sgn * partner * __sinf(ang)) * post;
          outp[((size_t)(b * 16 + hh) * 2048 + t) * 64 + dd] = __float2bfloat16(res);
        }
      }
    }
  } else {
    // ---- V region: acc rows are t-consecutive -> pack 4 t's into b64 stores ----
    const int b = bm >> 11;
    const int tt0 = (bm & 2047) + waveM * 64;
#pragma unroll
    for (int j = 0; j < 4; ++j) {
      const int n0 = bn + waveN * 64 + j * 16;
      const int hh = (n0 & 1023) >> 6;
      const int dd = (n0 & 63) + col;
      f16* dst = outv + (size_t)(b * 16 + hh) * 131072 + (size_t)dd * 2048;
#pragma unroll
      for (int i = 0; i < 4; ++i) {
        uint2 pk;
        pk.x = __builtin_bit_cast(unsigned, __builtin_amdgcn_cvt_pkrtz(acc[i][j][0], acc[i][j][1]));
        pk.y = __builtin_bit_cast(unsigned, __builtin_amdgcn_cvt_pkrtz(acc[i][j][2], acc[i][j][3]));
        *reinterpret_cast<uint2*>(dst + tt0 + i * 16 + quad * 4) = pk;
      }
    }
  }
}

// ---------------- output GEMM: out[4096,1024] = y[4096,1024] * Wout^T ----------------
// ROUND 13: split-K INSIDE the block. r12 audit: 64x64 K-loop costs ~2175 cyc/iter
// vs ~1000 cyc pipe work -- per-iteration stall (vmcnt+barrier+issue) dominates.
// Proven lever (attn r9, +8%): halve iteration count, double per-iter work.
// 512 thr / 8 waves: waves 0-3 compute K[0,512), waves 4-7 K[512,1024), each with
// own staging tiles; K-loop 32 -> 16 iters. Reduce: half-1 -> padded LDS Rs[64][65]
// (conflict-free), __syncthreads, half-0 adds + stores. No atomics.
// Grid (16,64) = 1024 blocks @ 2/CU = two clean residency waves, 16 waves/CU.
// LDS 48K staging + 16.6K Rs = 65.8K x 2 = 132K <= 160K.
__global__ __launch_bounds__(512, 4)
void gemm_out(const bf16* __restrict__ A, const bf16* __restrict__ B,
              float* __restrict__ outf) {
  __shared__ __align__(16) bf16 As[3][2][64 * 32];   // 24 KB: 3 bufs x 2 K-halves
  __shared__ __align__(16) bf16 Bs[3][2][64 * 32];   // 24 KB
  __shared__ float Rs[64][65];                       // 16.6 KB, padded (+1) f32
  const int K = 1024;
  const int tid = threadIdx.x;
  const int w = tid >> 6;          // 0..7
  const int kh = w >> 2;           // K-half 0/1
  const int wl = w & 3;            // wave id within half
  const int lane = tid & 63;
  const int quad = lane >> 4;
  const int col = lane & 15;
  const int waveM = wl >> 1;       // 0..1 -> 32-row half of tile
  const int waveN = wl & 1;        // 0..1 -> 32-col half
  const int bm = blockIdx.y * 64;
  const int bn = blockIdx.x * 64;
  const int kbase = kh * 512;

  f32x4 acc[2][2] = {};
  const int srow = lane >> 2;
  const int skoff = (((lane & 3) ^ ((srow >> 1) & 3))) * 8;
  const int swq = (quad ^ ((col >> 1) & 3)) * 8;

  // per K-half: 4 waves x 16 rows = 64 rows; 1 A-load + 1 B-load per wave per chunk
  auto stage = [&](int k0, int sb) {
    int r = wl * 16 + srow;
    load_lds16(A + (size_t)(bm + r) * K + kbase + k0 + skoff,
               (char*)As + (sb * 2 + kh) * 4096 + wl * 1024);
    load_lds16(B + (size_t)(bn + r) * K + kbase + k0 + skoff,
               (char*)Bs + (sb * 2 + kh) * 4096 + wl * 1024);
  };

  stage(0, 0);
  stage(32, 1);

  int cb = 0;
  for (int k0 = 0; k0 < 512; k0 += 32) {
    // per-wave outstanding: chunk k (2, oldest) + chunk k+1 (2) -> wait to 2
    if (k0 + 32 < 512) __asm__ volatile("s_waitcnt vmcnt(2)" ::: "memory");
    else               __asm__ volatile("s_waitcnt vmcnt(0)" ::: "memory");
    __asm__ volatile("s_barrier" ::: "memory");
    if (k0 + 64 < 512) {
      int nb = cb + 2; if (nb >= 3) nb -= 3;
      stage(k0 + 64, nb);
    }
    const bf16* at = &As[cb][kh][0];
    const bf16* bt = &Bs[cb][kh][0];
    bf16x8 af[2], bfr[2];
#pragma unroll
    for (int i = 0; i < 2; ++i)
      af[i] = *reinterpret_cast<const bf16x8*>(at + (waveM * 32 + i * 16 + col) * 32 + swq);
#pragma unroll
    for (int j = 0; j < 2; ++j)
      bfr[j] = *reinterpret_cast<const bf16x8*>(bt + (waveN * 32 + j * 16 + col) * 32 + swq);
#pragma unroll
    for (int i = 0; i < 2; ++i)
#pragma unroll
      for (int j = 0; j < 2; ++j)
        acc[i][j] = MFMA_BF(af[i], bfr[j], acc[i][j]);
    cb = (cb == 2) ? 0 : cb + 1;
  }

  // ---- cross-half reduce: half 1 -> LDS, half 0 adds + stores ----
  if (kh == 1) {
#pragma unroll
    for (int i = 0; i < 2; ++i)
#pragma unroll
      for (int j = 0; j < 2; ++j)
#pragma unroll
        for (int r = 0; r < 4; ++r)
          Rs[waveM * 32 + i * 16 + quad * 4 + r][waveN * 32 + j * 16 + col] = acc[i][j][r];
  }
  __syncthreads();
  if (kh == 0) {
#pragma unroll
    for (int i = 0; i < 2; ++i)
#pragma unroll
      for (int j = 0; j < 2; ++j) {
        const int nl = waveN * 32 + j * 16;
#pragma unroll
        for (int r = 0; r < 4; ++r) {
          const int ml = waveM * 32 + i * 16 + quad * 4 + r;
          outf[(size_t)(bm + ml) * 1024 + bn + nl + col] =
              acc[i][j][r] + Rs[ml][nl + col];
        }
      }
  }
}

// ---------------- flash attention: KVBLK=128, halved sync density ----------------
// FROZEN (r9-measured, ~44us): 128-key chunks as two 64-key sub-tiles, 1 sync per
// 128 keys, 80KB LDS = 2 blocks/CU, PV lags S by one chunk, XCD = bh%8 locality.
__global__ __launch_bounds__(256, 2)
void attn_kernel(const bf16* __restrict__ qh, const bf16* __restrict__ kh,
                 const f16* __restrict__ vt, bf16* __restrict__ y) {
  __shared__ __align__(16) bf16 Ks[2][2 * 64 * 64];   // 32 KB
  __shared__ __align__(16) f16 Vs[3][2 * 64 * 64];    // 48 KB

  const int bh = blockIdx.x;          // XCD = bh % 8
  const int qt = blockIdx.y;
  const int w = threadIdx.x >> 6;
  const int lane = threadIdx.x & 63;
  const int quad = lane >> 4;
  const int col = lane & 15;

  const int qrow0 = qt * 128 + w * 32 + col;
  bf16x8 qf[2][2];
#pragma unroll
  for (int f = 0; f < 2; ++f)
#pragma unroll
    for (int c = 0; c < 2; ++c)
      qf[f][c] = *reinterpret_cast<const bf16x8*>(
          qh + ((size_t)bh * 2048 + qrow0 + f * 16) * 64 + c * 32 + quad * 8);

  const int s8 = lane >> 3;
  const int blk = (lane & 7) ^ s8;
  const bf16* kg = kh + (size_t)bh * 2048 * 64;
  const f16* vg = vt + (size_t)bh * 64 * 2048;
  // kappa permutation for LDS row p = w*16 + 8L + s8 (per 64-key sub-tile)
  const int ks0 = 32 * (w >> 1) + 8 * ((4 * w + (s8 >> 2)) & 3) + 4 * (w & 1) + (s8 & 3);
  const int ks1 = 32 * (w >> 1) + 8 * ((4 * w + 2 + (s8 >> 2)) & 3) + 4 * (w & 1) + (s8 & 3);
  const int vrow0 = w * 16 + s8;   // V rows = d, identity keys

  const int csw = col & 7;
  const int sw0 = (quad ^ csw) * 8;
  const int sw1 = ((quad + 4) ^ csw) * 8;
  const int rdbase = col * 64;

  f32x4 O[2][4] = {};
  float l[2] = {};
  f16x8 pf[2][4];      // P fragments of the PREVIOUS 128-key chunk

  auto stageK2 = [&](int kn, int kb) {
    char* kbp = (char*)Ks + kb * 16384 + w * 2048;
    load_lds16(kg + (size_t)(kn + ks0) * 64 + blk * 8, kbp);
    load_lds16(kg + (size_t)(kn + ks1) * 64 + blk * 8, kbp + 1024);
    load_lds16(kg + (size_t)(kn + 64 + ks0) * 64 + blk * 8, kbp + 8192);
    load_lds16(kg + (size_t)(kn + 64 + ks1) * 64 + blk * 8, kbp + 8192 + 1024);
  };
  auto stageV2 = [&](int kn, int vb) {
    char* vbp = (char*)Vs + vb * 16384 + w * 2048;
    load_lds16(vg + (size_t)vrow0 * 2048 + kn + blk * 8, vbp);
    load_lds16(vg + (size_t)(vrow0 + 8) * 2048 + kn + blk * 8, vbp + 1024);
    load_lds16(vg + (size_t)vrow0 * 2048 + kn + 64 + blk * 8, vbp + 8192);
    load_lds16(vg + (size_t)(vrow0 + 8) * 2048 + kn + 64 + blk * 8, vbp + 8192 + 1024);
  };

  auto softmax = [&](f32x4 (&s)[2][2][4]) {
#pragma unroll
    for (int f = 0; f < 2; ++f) {
      unsigned pk[16];
      float lf = 0.0f;
#pragma unroll
      for (int u = 0; u < 2; ++u)
#pragma unroll
        for (int t = 0; t < 4; ++t) {
          float p0 = __builtin_amdgcn_exp2f(s[f][u][t][0]);
          float p1 = __builtin_amdgcn_exp2f(s[f][u][t][1]);
          float p2 = __builtin_amdgcn_exp2f(s[f][u][t][2]);
          float p3 = __builtin_amdgcn_exp2f(s[f][u][t][3]);
          lf += (p0 + p1) + (p2 + p3);
          pk[u * 8 + t * 2]     = __builtin_bit_cast(unsigned, __builtin_amdgcn_cvt_pkrtz(p0, p1));
          pk[u * 8 + t * 2 + 1] = __builtin_bit_cast(unsigned, __builtin_amdgcn_cvt_pkrtz(p2, p3));
        }
      l[f] += lf;
      pf[f][0] = __builtin_bit_cast(f16x8, (u32x4){pk[0], pk[1], pk[2], pk[3]});
      pf[f][1] = __builtin_bit_cast(f16x8, (u32x4){pk[4], pk[5], pk[6], pk[7]});
      pf[f][2] = __builtin_bit_cast(f16x8, (u32x4){pk[8], pk[9], pk[10], pk[11]});
      pf[f][3] = __builtin_bit_cast(f16x8, (u32x4){pk[12], pk[13], pk[14], pk[15]});
    }
  };

  // ---- prologue: chunk 0 staged; peeled iteration 0 (S + softmax only) ----
  stageK2(0, 0);
  stageV2(0, 0);

  __asm__ volatile("s_waitcnt vmcnt(4)" ::: "memory");   // K(0) done, V(0) x4 in flight
  __asm__ volatile("s_barrier" ::: "memory");
  stageK2(128, 1);
  stageV2(128, 1);
  {
    f32x4 s[2][2][4];
    __builtin_amdgcn_s_setprio(1);
#pragma unroll
    for (int u = 0; u < 2; ++u) {
      const bf16* kt = &Ks[0][u * 4096];
#pragma unroll
      for (int t = 0; t < 4; ++t) {
        bf16x8 kf0 = *reinterpret_cast<const bf16x8*>(kt + t * 1024 + rdbase + sw0);
        bf16x8 kf1 = *reinterpret_cast<const bf16x8*>(kt + t * 1024 + rdbase + sw1);
#pragma unroll
        for (int f = 0; f < 2; ++f) {
          f32x4 a = {};
          a = MFMA_BF(kf0, qf[f][0], a);
          a = MFMA_BF(kf1, qf[f][1], a);
          s[f][u][t] = a;
        }
      }
    }
    __builtin_amdgcn_s_setprio(0);
    softmax(s);
  }

  // ---- main loop c = 1..15: S(c) + PV(c-1) fused MFMA cluster, 1 sync/128 keys ----
  int vprev = 0;
  int vnext = 2;
#pragma unroll 1
  for (int c = 1; c < 16; ++c) {
    const int kc = c * 128;
    __asm__ volatile("s_waitcnt vmcnt(4)" ::: "memory");
    __asm__ volatile("s_barrier" ::: "memory");
    if (c + 1 < 16) {
      stageK2(kc + 128, (c + 1) & 1);
      stageV2(kc + 128, vnext);
    }

    f32x4 s[2][2][4];
    __builtin_amdgcn_s_setprio(1);
#pragma unroll
    for (int u = 0; u < 2; ++u) {
      const bf16* kt = &Ks[c & 1][u * 4096];
      const f16* vtile = &Vs[vprev][u * 4096];
#pragma unroll
      for (int t = 0; t < 4; ++t) {
        bf16x8 kf0 = *reinterpret_cast<const bf16x8*>(kt + t * 1024 + rdbase + sw0);
        bf16x8 kf1 = *reinterpret_cast<const bf16x8*>(kt + t * 1024 + rdbase + sw1);
        f16x8 vf0 = *reinterpret_cast<const f16x8*>(vtile + t * 1024 + rdbase + sw0);
        f16x8 vf1 = *reinterpret_cast<const f16x8*>(vtile + t * 1024 + rdbase + sw1);
#pragma unroll
        for (int f = 0; f < 2; ++f) {
          f32x4 a = {};
          a = MFMA_BF(kf0, qf[f][0], a);
          a = MFMA_BF(kf1, qf[f][1], a);
          s[f][u][t] = a;
          O[f][t] = MFMA_F16(vf0, pf[f][u * 2], O[f][t]);
          O[f][t] = MFMA_F16(vf1, pf[f][u * 2 + 1], O[f][t]);
        }
      }
    }
    __builtin_amdgcn_s_setprio(0);
    softmax(s);

    vprev = (vprev == 2) ? 0 : vprev + 1;
    vnext = (vnext == 2) ? 0 : vnext + 1;
  }

  // ---- epilogue: final PV for chunk 15 ----
  __asm__ volatile("s_waitcnt vmcnt(0)" ::: "memory");
  __asm__ volatile("s_barrier" ::: "memory");
  {
    __builtin_amdgcn_s_setprio(1);
#pragma unroll
    for (int u = 0; u < 2; ++u) {
      const f16* vtile = &Vs[vprev][u * 4096];
#pragma unroll
      for (int t = 0; t < 4; ++t) {
        f16x8 vf0 = *reinterpret_cast<const f16x8*>(vtile + t * 1024 + rdbase + sw0);
        f16x8 vf1 = *reinterpret_cast<const f16x8*>(vtile + t * 1024 + rdbase + sw1);
#pragma unroll
        for (int f = 0; f < 2; ++f) {
          O[f][t] = MFMA_F16(vf0, pf[f][u * 2], O[f][t]);
          O[f][t] = MFMA_F16(vf1, pf[f][u * 2 + 1], O[f][t]);
        }
      }
    }
    __builtin_amdgcn_s_setprio(0);
  }

  // ---- reduce l over quads, normalize, direct y write ----
  const int b = bh >> 4, h = bh & 15;
#pragma unroll
  for (int f = 0; f < 2; ++f) {
    float lv = l[f];
    lv += __shfl_xor(lv, 16, 64);
    lv += __shfl_xor(lv, 32, 64);
    float inv = 1.0f / lv;
    int tq = qt * 128 + w * 32 + f * 16 + col;
    size_t base = ((size_t)b * 2048 + tq) * 1024 + h * 64;
#pragma unroll
    for (int j = 0; j < 4; ++j) {
      uint2 pk2;
      pk2.x = pk_bf16(O[f][j][0] * inv, O[f][j][1] * inv);
      pk2.y = pk_bf16(O[f][j][2] * inv, O[f][j][3] * inv);
      *reinterpret_cast<uint2*>((unsigned short*)y + base + j * 16 + quad * 4) = pk2;
    }
  }
}

extern "C" void kernel_launch(void* const* d_in, const int* in_sizes, int n_in,
                              void* d_out, int out_size, void* d_ws, size_t ws_size,
                              hipStream_t stream) {
  const float* x    = (const float*)d_in[0];
  const float* wqkv = (const float*)d_in[1];
  const float* wout = (const float*)d_in[2];
  float* out = (float*)d_out;
  char* ws = (char*)d_ws;

  bf16* xb    = (bf16*)(ws);                        // 8 MB (dead after gemm_qkv)
  bf16* wqkvb = (bf16*)(ws + (size_t)(8 << 20));    // 6 MB
  bf16* woutb = (bf16*)(ws + (size_t)(14 << 20));   // 2 MB
  bf16* qh    = (bf16*)(ws + (size_t)(16 << 20));   // 8 MB
  bf16* kh    = (bf16*)(ws + (size_t)(24 << 20));   // 8 MB
  f16*  vt    = (f16*) (ws + (size_t)(32 << 20));   // 8 MB
  bf16* y     = (bf16*)(ws);                        // 8 MB, overlays dead xb (40 MB)

  cvt_all<<<8192, 256, 0, stream>>>(x, wqkv, wout,
                                    (unsigned*)xb, (unsigned*)wqkvb, (unsigned*)woutb);
  gemm_qkv<<<dim3(24, 32), 256, 0, stream>>>(xb, wqkvb, qh, kh, vt);
  attn_kernel<<<dim3(32, 16), 256, 0, stream>>>(qh, kh, vt, y);
  gemm_out<<<dim3(16, 64), 512, 0, stream>>>(y, woutb, out);
}